// Round 5
// baseline (568.118 us; speedup 1.0000x reference)
//
#include <hip/hip_runtime.h>
#include <stdint.h>

// ContinuousConvolution, MI355X gfx950. Round 5: fp32 selection with
// XLA/Eigen-matching d2: dot = fma(z,qz, fma(y,qy, x*qx)) (Eigen gebp FMA
// chain, ascending k), sq and combine strict IEEE left-to-right. Selection
// ranks by fp32 (d2bits, idx) keys == top_k(-d2) order with index tie-break.
//   Kernel A: exact KNN (K=16) w.r.t. this d2, 1 wave/query.
//   Kernel B: fused gather + 3-layer MLP + (sum, maxpool, attentive-aggr), fp32 VALU.

typedef unsigned int   u32;
typedef unsigned long long u64;

#define NPTS  8192
#define KNB   16
#define CHUNK 1024
#define SCAP  512   // survivor cap/query; E[cnt]~128
#define QPW   4     // queries per wave in MLP kernel

// order-preserving map: float bits -> u32, unsigned compare == total order
__device__ __forceinline__ u32 fordkey(float f) {
    u32 u = __float_as_uint(f);
    return u ^ ((u32)((int)u >> 31) | 0x80000000u);
}
__device__ __forceinline__ u64 shflxor64(u64 v, int m) {
    int lo = __shfl_xor((int)(u32)v, m, 64);
    int hi = __shfl_xor((int)(u32)(v >> 32), m, 64);
    return ((u64)(u32)hi << 32) | (u32)lo;
}
// Reference-matching d2:
//   dot: Eigen gebp FMA chain, k ascending (first fma vs 0 == plain rounded mul)
//   sq:  strict (x*x + y*y) + z*z  (LLVM IR path, no contraction)
//   d2:  (qsq + sq) - 2*dot        (elementwise HLO, strict)
__device__ __forceinline__ float dot_ref(float qx, float qy, float qz,
                                         float x, float y, float z) {
    return fmaf(z, qz, fmaf(y, qy, __fmul_rn(x, qx)));
}
__device__ __forceinline__ float sq_np32(float x, float y, float z) {
    return __fadd_rn(__fadd_rn(__fmul_rn(x, x), __fmul_rn(y, y)), __fmul_rn(z, z));
}
__device__ __forceinline__ float d2_ref(float qx, float qy, float qz, float qsq,
                                        float x, float y, float z, float sq) {
    float dot = dot_ref(qx, qy, qz, x, y, z);
    return __fsub_rn(__fadd_rn(qsq, sq), __fmul_rn(2.0f, dot));
}

template <int N>
__device__ __forceinline__ void bitonic_sort(u64* k) {
#pragma unroll
    for (int size = 2; size <= N; size <<= 1) {
#pragma unroll
        for (int stride = size >> 1; stride > 0; stride >>= 1) {
#pragma unroll
            for (int i = 0; i < N; ++i) {
                int j = i ^ stride;
                if (j > i) {
                    bool up = ((i & size) == 0);
                    u64 x = k[i], y = k[j];
                    bool sw = up ? (x > y) : (x < y);
                    k[i] = sw ? y : x;
                    k[j] = sw ? x : y;
                }
            }
        }
    }
}

// ---------------- Kernel A: KNN ----------------
// grid (NPTS/4, 2), block 256 = 4 waves, 1 wave per query.
__global__ __launch_bounds__(256) void knn_kernel(const float* __restrict__ coords,
                                                  int* __restrict__ idx_out) {
    __shared__ float4 cbuf[CHUNK];       // staged candidate (x,y,z,sq)
    __shared__ u64    surv[4][SCAP];     // per-wave survivor keys (d2bits, idx)
    __shared__ int    scnt[4];

    const int w    = threadIdx.x >> 6;
    const int lane = threadIdx.x & 63;
    const int b    = blockIdx.y;
    const int q    = blockIdx.x * 4 + w;
    const float* cb = coords + (size_t)b * NPTS * 3;

    float qx = cb[q * 3 + 0];
    float qy = cb[q * 3 + 1];
    float qz = cb[q * 3 + 2];
    float qsq = sq_np32(qx, qy, qz);

    if (lane == 0) scnt[w] = 0;
    u64 tau = ~0ull;

    for (int chunk = 0; chunk < NPTS / CHUNK; ++chunk) {
        __syncthreads();
        for (int s = threadIdx.x; s < CHUNK; s += 256) {
            int c = chunk * CHUNK + s;
            float x = cb[c * 3 + 0];
            float y = cb[c * 3 + 1];
            float z = cb[c * 3 + 2];
            cbuf[s] = make_float4(x, y, z, sq_np32(x, y, z));
        }
        __syncthreads();

        if (chunk == 0) {
            // Phase 1: exact 16-smallest keys of first 1024 -> seeds + tau
            u64 kk[16];
#pragma unroll
            for (int i = 0; i < 16; ++i) {
                int s = i * 64 + lane;
                float4 c = cbuf[s];
                float d2 = d2_ref(qx, qy, qz, qsq, c.x, c.y, c.z, c.w);
                kk[i] = ((u64)fordkey(d2) << 32) | (u32)s;
            }
            bitonic_sort<16>(kk);
#pragma unroll 1
            for (int r = 0; r < 16; ++r) {
                u64 m = kk[0];
#pragma unroll
                for (int d = 1; d < 64; d <<= 1) {
                    u64 o = shflxor64(m, d);
                    m = (o < m) ? o : m;
                }
                if (lane == 0) surv[w][r] = m;   // seed survivors (chunk-0 top16)
                if (kk[0] == m) {                // unique keys -> exactly one lane pops
#pragma unroll
                    for (int j = 0; j < 15; ++j) kk[j] = kk[j + 1];
                    kk[15] = ~0ull;
                }
                tau = m;                          // after last round: 16th-smallest key
            }
            if (lane == 0) scnt[w] = 16;
        } else {
            // Phase 2: filter-scan, append survivors (key <= tau is exact:
            // global top-16 keys are all <= chunk-0's 16th key)
#pragma unroll 4
            for (int i = 0; i < CHUNK / 64; ++i) {
                int s = i * 64 + lane;
                float4 c = cbuf[s];
                float d2 = d2_ref(qx, qy, qz, qsq, c.x, c.y, c.z, c.w);
                u64 key = ((u64)fordkey(d2) << 32) | (u32)(chunk * CHUNK + s);
                if (key <= tau) {
                    int pos = atomicAdd(&scnt[w], 1);
                    if (pos < SCAP) surv[w][pos] = key;
                }
            }
        }
    }
    __syncthreads();

    // Phase 3: exact top-16 of survivors (>=16 guaranteed by seeds)
    int cnt = scnt[w]; if (cnt > SCAP) cnt = SCAP;
    u64 a[8];
#pragma unroll
    for (int j = 0; j < 8; ++j) {
        int p = j * 64 + lane;
        a[j] = (p < cnt) ? surv[w][p] : ~0ull;
    }
    bitonic_sort<8>(a);
    int myidx = 0;
#pragma unroll 1
    for (int r = 0; r < 16; ++r) {
        u64 m = a[0];
#pragma unroll
        for (int d = 1; d < 64; d <<= 1) {
            u64 o = shflxor64(m, d);
            m = (o < m) ? o : m;
        }
        if (a[0] == m) {
#pragma unroll
            for (int j = 0; j < 7; ++j) a[j] = a[j + 1];
            a[7] = ~0ull;
        }
        if (lane == r) myidx = (int)(u32)(m & 0xffffffffu);
    }
    if (lane < KNB) idx_out[((size_t)b * NPTS + q) * KNB + lane] = myidx;
}

// ---------------- Kernel B: gather + MLP + outputs ----------------
__global__ __launch_bounds__(256, 2) void mlp_kernel(
    const float* __restrict__ pf, const float* __restrict__ coords,
    const float* __restrict__ w1, const float* __restrict__ b1,
    const float* __restrict__ w2, const float* __restrict__ b2,
    const float* __restrict__ w3, const float* __restrict__ b3,
    const float* __restrict__ aw, const float* __restrict__ ab,
    const int* __restrict__ knn_idx, float* __restrict__ out) {

    __shared__ float w1s[32 * 67];
    __shared__ float w2s[64 * 32];
    __shared__ float w3s[64 * 64];
    __shared__ float b1s[32], b2s[64], b3s[64], aws[16], ab_s;
    __shared__ __attribute__((aligned(16))) float gbuf[4][16][68];   // g / reused as h2
    __shared__ __attribute__((aligned(16))) float h1buf[4][16][36];  // rows 16B-aligned

    for (int i = threadIdx.x; i < 32 * 67; i += 256) w1s[i] = w1[i];
    for (int i = threadIdx.x; i < 64 * 32; i += 256) w2s[i] = w2[i];
    for (int i = threadIdx.x; i < 64 * 64; i += 256) w3s[i] = w3[i];
    if (threadIdx.x < 32)                            b1s[threadIdx.x]       = b1[threadIdx.x];
    if (threadIdx.x >= 64  && threadIdx.x < 128)     b2s[threadIdx.x - 64]  = b2[threadIdx.x - 64];
    if (threadIdx.x >= 128 && threadIdx.x < 192)     b3s[threadIdx.x - 128] = b3[threadIdx.x - 128];
    if (threadIdx.x >= 192 && threadIdx.x < 208)     aws[threadIdx.x - 192] = aw[threadIdx.x - 192];
    if (threadIdx.x == 255)                          ab_s = ab[0];
    __syncthreads();

    const int w    = threadIdx.x >> 6;
    const int lane = threadIdx.x & 63;

    float w1r[68];
    {
        int r = lane & 31;
#pragma unroll
        for (int c = 0; c < 67; ++c) w1r[c] = w1s[r * 67 + c];
        w1r[67] = 0.0f;  // pairs with gbuf[..][67] = 0 pad
    }
    float w2r[32];
#pragma unroll
    for (int c = 0; c < 32; ++c) w2r[c] = w2s[lane * 32 + c];
    float w3r[64];
#pragma unroll
    for (int c = 0; c < 64; ++c) w3r[c] = w3s[lane * 64 + c];
    float b1v = b1s[lane & 31], b2v = b2s[lane], b3v = b3s[lane];

    const int gw = blockIdx.x * 4 + w;

    for (int t = 0; t < QPW; ++t) {
        int gq = gw * QPW + t;            // 0..16383
        int b  = gq >> 13;
        const int* idxp = knn_idx + (size_t)gq * KNB;
        int myi = (lane < KNB) ? (idxp[lane] & (NPTS - 1)) : 0;  // mask: OOB-proof

        float pool = -3.0e38f;
#pragma unroll 1
        for (int k = 0; k < 16; ++k) {
            int nk = __shfl(myi, k, 64);
            float v = pf[((size_t)b * NPTS + nk) * 64 + lane];
            gbuf[w][k][lane] = v;
            pool = fmaxf(pool, v);
        }
        int ksrc = lane & 15;
        int nk2 = __shfl(myi, ksrc, 64);
        int i0  = __shfl(myi, 0, 64);
        if (lane < 48) {  // rel coords: k = lane&15, j = lane>>4
            int j = lane >> 4;
            float ck = coords[((size_t)b * NPTS + nk2) * 3 + j];
            float c0 = coords[((size_t)b * NPTS + i0) * 3 + j];
            gbuf[w][ksrc][64 + j] = ck - c0;
        }
        if (lane < 16) gbuf[w][lane][67] = 0.0f;
        __syncthreads();

        // layer 1: 32 ch; lanes<32 -> k 0..7, lanes>=32 -> k 8..15
        float h1a[8];
        {
            int kk = (lane >> 5) * 8;
#pragma unroll 1
            for (int k = 0; k < 8; ++k) {
                float acc = b1v;
                const float4* gp = (const float4*)(&gbuf[w][kk + k][0]);
#pragma unroll
                for (int c4 = 0; c4 < 17; ++c4) {
                    float4 g4 = gp[c4];
                    acc = fmaf(g4.x, w1r[c4 * 4 + 0], acc);
                    acc = fmaf(g4.y, w1r[c4 * 4 + 1], acc);
                    acc = fmaf(g4.z, w1r[c4 * 4 + 2], acc);
                    acc = fmaf(g4.w, w1r[c4 * 4 + 3], acc);
                }
                h1a[k] = acc;
            }
            int ch = lane & 31;
#pragma unroll
            for (int k = 0; k < 8; ++k) h1buf[w][kk + k][ch] = h1a[k];
        }
        __syncthreads();

        // layer 2: 64 ch, lane = channel, all k
        float h2a[16];
#pragma unroll 1
        for (int k = 0; k < 16; ++k) {
            float acc = b2v;
            const float4* hp = (const float4*)(&h1buf[w][k][0]);
#pragma unroll
            for (int c4 = 0; c4 < 8; ++c4) {
                float4 h4 = hp[c4];
                acc = fmaf(h4.x, w2r[c4 * 4 + 0], acc);
                acc = fmaf(h4.y, w2r[c4 * 4 + 1], acc);
                acc = fmaf(h4.z, w2r[c4 * 4 + 2], acc);
                acc = fmaf(h4.w, w2r[c4 * 4 + 3], acc);
            }
            h2a[k] = acc;
        }
        __syncthreads();
#pragma unroll
        for (int k = 0; k < 16; ++k) gbuf[w][k][lane] = h2a[k];  // reuse as h2 buffer
        __syncthreads();

        // layer 3 + epilogue (lane-local)
        float osum = 0.0f, oagg = 0.0f;
#pragma unroll 1
        for (int k = 0; k < 16; ++k) {
            float acc = b3v;
            const float4* hp = (const float4*)(&gbuf[w][k][0]);
#pragma unroll
            for (int c4 = 0; c4 < 16; ++c4) {
                float4 h4 = hp[c4];
                acc = fmaf(h4.x, w3r[c4 * 4 + 0], acc);
                acc = fmaf(h4.y, w3r[c4 * 4 + 1], acc);
                acc = fmaf(h4.z, w3r[c4 * 4 + 2], acc);
                acc = fmaf(h4.w, w3r[c4 * 4 + 3], acc);
            }
            osum += acc;
            oagg = fmaf(aws[k], acc, oagg);
        }
        oagg += ab_s;

        float* op = out + (size_t)gq * 192;
        op[lane]       = osum;
        op[64 + lane]  = pool;
        op[128 + lane] = oagg;
        __syncthreads();
    }
}

extern "C" void kernel_launch(void* const* d_in, const int* in_sizes, int n_in,
                              void* d_out, int out_size, void* d_ws, size_t ws_size,
                              hipStream_t stream) {
    const float* pf     = (const float*)d_in[0];
    const float* coords = (const float*)d_in[1];
    const float* w1     = (const float*)d_in[2];
    const float* b1     = (const float*)d_in[3];
    const float* w2     = (const float*)d_in[4];
    const float* b2     = (const float*)d_in[5];
    const float* w3     = (const float*)d_in[6];
    const float* b3     = (const float*)d_in[7];
    const float* aw     = (const float*)d_in[8];
    const float* ab     = (const float*)d_in[9];
    int* knn_idx = (int*)d_ws;                 // [2][8192][16] int32 = 1 MB
    float* outp  = (float*)d_out;              // [2][8192][192] fp32

    dim3 gA(NPTS / 4, 2);
    knn_kernel<<<gA, 256, 0, stream>>>(coords, knn_idx);

    int blocksB = (2 * NPTS) / (4 * QPW);      // 1024
    mlp_kernel<<<blocksB, 256, 0, stream>>>(pf, coords, w1, b1, w2, b2, w3, b3,
                                            aw, ab, knn_idx, outp);
}

// Round 6
// 290.669 us; speedup vs baseline: 1.9545x; 1.9545x over previous
//
#include <hip/hip_runtime.h>
#include <stdint.h>

// ContinuousConvolution, MI355X gfx950. Round 6: algebraic collapse of the
// linear MLP (sum/aggr outputs commute with the MLP) -> 2 vectors/query
// instead of 16; mlp_kernel becomes 1 wave/block (no inter-wave coupling),
// weights in registers, <1 KB LDS. KNN kernel unchanged from round 5 (verified).

typedef unsigned int   u32;
typedef unsigned long long u64;

#define NPTS  8192
#define KNB   16
#define CHUNK 1024
#define SCAP  512
#define QPW   4     // queries per wave in MLP kernel

__device__ __forceinline__ u32 fordkey(float f) {
    u32 u = __float_as_uint(f);
    return u ^ ((u32)((int)u >> 31) | 0x80000000u);
}
__device__ __forceinline__ u64 shflxor64(u64 v, int m) {
    int lo = __shfl_xor((int)(u32)v, m, 64);
    int hi = __shfl_xor((int)(u32)(v >> 32), m, 64);
    return ((u64)(u32)hi << 32) | (u32)lo;
}
// Reference-matching d2 (verified round 5):
//   dot: Eigen gebp FMA chain; sq & combine strict IEEE left-to-right.
__device__ __forceinline__ float dot_ref(float qx, float qy, float qz,
                                         float x, float y, float z) {
    return fmaf(z, qz, fmaf(y, qy, __fmul_rn(x, qx)));
}
__device__ __forceinline__ float sq_np32(float x, float y, float z) {
    return __fadd_rn(__fadd_rn(__fmul_rn(x, x), __fmul_rn(y, y)), __fmul_rn(z, z));
}
__device__ __forceinline__ float d2_ref(float qx, float qy, float qz, float qsq,
                                        float x, float y, float z, float sq) {
    float dot = dot_ref(qx, qy, qz, x, y, z);
    return __fsub_rn(__fadd_rn(qsq, sq), __fmul_rn(2.0f, dot));
}

template <int N>
__device__ __forceinline__ void bitonic_sort(u64* k) {
#pragma unroll
    for (int size = 2; size <= N; size <<= 1) {
#pragma unroll
        for (int stride = size >> 1; stride > 0; stride >>= 1) {
#pragma unroll
            for (int i = 0; i < N; ++i) {
                int j = i ^ stride;
                if (j > i) {
                    bool up = ((i & size) == 0);
                    u64 x = k[i], y = k[j];
                    bool sw = up ? (x > y) : (x < y);
                    k[i] = sw ? y : x;
                    k[j] = sw ? x : y;
                }
            }
        }
    }
}

// ---------------- Kernel A: KNN (unchanged from round 5) ----------------
__global__ __launch_bounds__(256) void knn_kernel(const float* __restrict__ coords,
                                                  int* __restrict__ idx_out) {
    __shared__ float4 cbuf[CHUNK];
    __shared__ u64    surv[4][SCAP];
    __shared__ int    scnt[4];

    const int w    = threadIdx.x >> 6;
    const int lane = threadIdx.x & 63;
    const int b    = blockIdx.y;
    const int q    = blockIdx.x * 4 + w;
    const float* cb = coords + (size_t)b * NPTS * 3;

    float qx = cb[q * 3 + 0];
    float qy = cb[q * 3 + 1];
    float qz = cb[q * 3 + 2];
    float qsq = sq_np32(qx, qy, qz);

    if (lane == 0) scnt[w] = 0;
    u64 tau = ~0ull;

    for (int chunk = 0; chunk < NPTS / CHUNK; ++chunk) {
        __syncthreads();
        for (int s = threadIdx.x; s < CHUNK; s += 256) {
            int c = chunk * CHUNK + s;
            float x = cb[c * 3 + 0];
            float y = cb[c * 3 + 1];
            float z = cb[c * 3 + 2];
            cbuf[s] = make_float4(x, y, z, sq_np32(x, y, z));
        }
        __syncthreads();

        if (chunk == 0) {
            u64 kk[16];
#pragma unroll
            for (int i = 0; i < 16; ++i) {
                int s = i * 64 + lane;
                float4 c = cbuf[s];
                float d2 = d2_ref(qx, qy, qz, qsq, c.x, c.y, c.z, c.w);
                kk[i] = ((u64)fordkey(d2) << 32) | (u32)s;
            }
            bitonic_sort<16>(kk);
#pragma unroll 1
            for (int r = 0; r < 16; ++r) {
                u64 m = kk[0];
#pragma unroll
                for (int d = 1; d < 64; d <<= 1) {
                    u64 o = shflxor64(m, d);
                    m = (o < m) ? o : m;
                }
                if (lane == 0) surv[w][r] = m;
                if (kk[0] == m) {
#pragma unroll
                    for (int j = 0; j < 15; ++j) kk[j] = kk[j + 1];
                    kk[15] = ~0ull;
                }
                tau = m;
            }
            if (lane == 0) scnt[w] = 16;
        } else {
#pragma unroll 4
            for (int i = 0; i < CHUNK / 64; ++i) {
                int s = i * 64 + lane;
                float4 c = cbuf[s];
                float d2 = d2_ref(qx, qy, qz, qsq, c.x, c.y, c.z, c.w);
                u64 key = ((u64)fordkey(d2) << 32) | (u32)(chunk * CHUNK + s);
                if (key <= tau) {
                    int pos = atomicAdd(&scnt[w], 1);
                    if (pos < SCAP) surv[w][pos] = key;
                }
            }
        }
    }
    __syncthreads();

    int cnt = scnt[w]; if (cnt > SCAP) cnt = SCAP;
    u64 a[8];
#pragma unroll
    for (int j = 0; j < 8; ++j) {
        int p = j * 64 + lane;
        a[j] = (p < cnt) ? surv[w][p] : ~0ull;
    }
    bitonic_sort<8>(a);
    int myidx = 0;
#pragma unroll 1
    for (int r = 0; r < 16; ++r) {
        u64 m = a[0];
#pragma unroll
        for (int d = 1; d < 64; d <<= 1) {
            u64 o = shflxor64(m, d);
            m = (o < m) ? o : m;
        }
        if (a[0] == m) {
#pragma unroll
            for (int j = 0; j < 7; ++j) a[j] = a[j + 1];
            a[7] = ~0ull;
        }
        if (lane == r) myidx = (int)(u32)(m & 0xffffffffu);
    }
    if (lane < KNB) idx_out[((size_t)b * NPTS + q) * KNB + lane] = myidx;
}

// ---------------- Kernel B: gather + collapsed MLP ----------------
// 1 wave per block, QPW queries per wave. Linear MLP => push the K-sums
// through: out_sum = W3(W2(W1*Sum(g) + 16*b1) + 16*b2) + 16*b3,
//          y_aggr = W3(W2(W1*Sum(aw*g) + sa*b1) + sa*b2) + sa*b3 + ab.
__global__ __launch_bounds__(64) void mlp_kernel(
    const float* __restrict__ pf, const float* __restrict__ coords,
    const float* __restrict__ w1, const float* __restrict__ b1,
    const float* __restrict__ w2, const float* __restrict__ b2,
    const float* __restrict__ w3, const float* __restrict__ b3,
    const float* __restrict__ aw, const float* __restrict__ ab,
    const int* __restrict__ knn_idx, float* __restrict__ out) {

    __shared__ __attribute__((aligned(16))) float vbuf[2][68];   // [0]=Sum(g), [1]=Sum(aw*g); reused for h2
    __shared__ __attribute__((aligned(16))) float h1buf[2][36];

    const int lane = threadIdx.x;            // 0..63
    const int r    = lane & 31;
    const int vec  = lane >> 5;

    // weights in registers
    float w1r[68];
#pragma unroll
    for (int c = 0; c < 67; ++c) w1r[c] = w1[r * 67 + c];
    w1r[67] = 0.0f;
    float w2r[32];
    {
        const float4* p = (const float4*)(w2 + lane * 32);
#pragma unroll
        for (int c4 = 0; c4 < 8; ++c4) {
            float4 v = p[c4];
            w2r[c4 * 4 + 0] = v.x; w2r[c4 * 4 + 1] = v.y;
            w2r[c4 * 4 + 2] = v.z; w2r[c4 * 4 + 3] = v.w;
        }
    }
    float w3r[64];
    {
        const float4* p = (const float4*)(w3 + lane * 64);
#pragma unroll
        for (int c4 = 0; c4 < 16; ++c4) {
            float4 v = p[c4];
            w3r[c4 * 4 + 0] = v.x; w3r[c4 * 4 + 1] = v.y;
            w3r[c4 * 4 + 2] = v.z; w3r[c4 * 4 + 3] = v.w;
        }
    }
    float awr[16];
#pragma unroll
    for (int k = 0; k < 16; ++k) awr[k] = aw[k];
    float sa = 0.0f;
#pragma unroll
    for (int k = 0; k < 16; ++k) sa += awr[k];
    const float b1v = b1[r], b2v = b2[lane], b3v = b3[lane], abv = ab[0];
    const float c1 = (vec == 0) ? 16.0f : sa;   // bias coefficient for my vec

#pragma unroll 1
    for (int t = 0; t < QPW; ++t) {
        const int gq = blockIdx.x * QPW + t;     // 0..16383
        const int b  = gq >> 13;
        const float* pfb = pf + (size_t)b * NPTS * 64;
        const float* cb  = coords + (size_t)b * NPTS * 3;

        int myi = knn_idx[(size_t)gq * KNB + (lane & 15)] & (NPTS - 1);

        // gather + lane-local pool / Sum(g) / Sum(aw*g)  (lane = channel)
        float pool = -3.0e38f, G1 = 0.0f, Ga = 0.0f;
#pragma unroll
        for (int k = 0; k < 16; ++k) {
            int nk = __shfl(myi, k, 64);
            float v = pfb[nk * 64 + lane];
            pool = fmaxf(pool, v);
            G1 += v;
            Ga = fmaf(awr[k], v, Ga);
        }
        vbuf[0][lane] = G1;
        vbuf[1][lane] = Ga;

        // rel-coord channels 64..66: Sum_k(c_k - c_0) and Sum_k aw_k(c_k - c_0)
        if (lane < 48) {
            int j  = lane >> 4;                  // coord component
            int i0 = __shfl(myi, 0, 64);
            float rel  = cb[myi * 3 + j] - cb[i0 * 3 + j];   // k = lane&15
            float wrel = awr[lane & 15] * rel;
#pragma unroll
            for (int d = 1; d < 16; d <<= 1) {
                rel  += __shfl_xor(rel, d, 64);
                wrel += __shfl_xor(wrel, d, 64);
            }
            if ((lane & 15) == 0) { vbuf[0][64 + j] = rel; vbuf[1][64 + j] = wrel; }
        }
        if (lane == 0) { vbuf[0][67] = 0.0f; vbuf[1][67] = 0.0f; }
        __syncthreads();                         // 1 wave: ~free

        // layer 1: lane -> channel r of vector `vec`
        float acc = c1 * b1v;
        {
            const float4* vp = (const float4*)(&vbuf[vec][0]);
#pragma unroll
            for (int c4 = 0; c4 < 17; ++c4) {
                float4 g4 = vp[c4];
                acc = fmaf(g4.x, w1r[c4 * 4 + 0], acc);
                acc = fmaf(g4.y, w1r[c4 * 4 + 1], acc);
                acc = fmaf(g4.z, w1r[c4 * 4 + 2], acc);
                acc = fmaf(g4.w, w1r[c4 * 4 + 3], acc);
            }
        }
        h1buf[vec][r] = acc;
        __syncthreads();

        // layer 2: lane -> channel `lane` of BOTH vectors
        float a0 = 16.0f * b2v, a1 = sa * b2v;
        {
            const float4* p0 = (const float4*)(&h1buf[0][0]);
            const float4* p1 = (const float4*)(&h1buf[1][0]);
#pragma unroll
            for (int c4 = 0; c4 < 8; ++c4) {
                float4 x0 = p0[c4], x1 = p1[c4];
                a0 = fmaf(x0.x, w2r[c4 * 4 + 0], a0);
                a0 = fmaf(x0.y, w2r[c4 * 4 + 1], a0);
                a0 = fmaf(x0.z, w2r[c4 * 4 + 2], a0);
                a0 = fmaf(x0.w, w2r[c4 * 4 + 3], a0);
                a1 = fmaf(x1.x, w2r[c4 * 4 + 0], a1);
                a1 = fmaf(x1.y, w2r[c4 * 4 + 1], a1);
                a1 = fmaf(x1.z, w2r[c4 * 4 + 2], a1);
                a1 = fmaf(x1.w, w2r[c4 * 4 + 3], a1);
            }
        }
        __syncthreads();                         // layer-1 vbuf reads are done (in-order wave)
        vbuf[0][lane] = a0;
        vbuf[1][lane] = a1;
        __syncthreads();

        // layer 3 + outputs (lane = out channel)
        float s1 = 16.0f * b3v, sA = sa * b3v;
        {
            const float4* p0 = (const float4*)(&vbuf[0][0]);
            const float4* p1 = (const float4*)(&vbuf[1][0]);
#pragma unroll
            for (int c4 = 0; c4 < 16; ++c4) {
                float4 x0 = p0[c4], x1 = p1[c4];
                s1 = fmaf(x0.x, w3r[c4 * 4 + 0], s1);
                s1 = fmaf(x0.y, w3r[c4 * 4 + 1], s1);
                s1 = fmaf(x0.z, w3r[c4 * 4 + 2], s1);
                s1 = fmaf(x0.w, w3r[c4 * 4 + 3], s1);
                sA = fmaf(x1.x, w3r[c4 * 4 + 0], sA);
                sA = fmaf(x1.y, w3r[c4 * 4 + 1], sA);
                sA = fmaf(x1.z, w3r[c4 * 4 + 2], sA);
                sA = fmaf(x1.w, w3r[c4 * 4 + 3], sA);
            }
        }
        float* op = out + (size_t)gq * 192;
        op[lane]       = s1;
        op[64 + lane]  = pool;
        op[128 + lane] = sA + abv;
        __syncthreads();                         // before next query reuses vbuf/h1buf
    }
}

extern "C" void kernel_launch(void* const* d_in, const int* in_sizes, int n_in,
                              void* d_out, int out_size, void* d_ws, size_t ws_size,
                              hipStream_t stream) {
    const float* pf     = (const float*)d_in[0];
    const float* coords = (const float*)d_in[1];
    const float* w1     = (const float*)d_in[2];
    const float* b1     = (const float*)d_in[3];
    const float* w2     = (const float*)d_in[4];
    const float* b2     = (const float*)d_in[5];
    const float* w3     = (const float*)d_in[6];
    const float* b3     = (const float*)d_in[7];
    const float* aw     = (const float*)d_in[8];
    const float* ab     = (const float*)d_in[9];
    int* knn_idx = (int*)d_ws;                 // [2][8192][16] int32 = 1 MB
    float* outp  = (float*)d_out;              // [2][8192][192] fp32

    dim3 gA(NPTS / 4, 2);
    knn_kernel<<<gA, 256, 0, stream>>>(coords, knn_idx);

    int blocksB = (2 * NPTS) / QPW;            // 4096 one-wave blocks
    mlp_kernel<<<blocksB, 64, 0, stream>>>(pf, coords, w1, b1, w2, b2, w3, b3,
                                           aw, ab, knn_idx, outp);
}

// Round 7
// 248.614 us; speedup vs baseline: 2.2851x; 1.1692x over previous
//
#include <hip/hip_runtime.h>
#include <stdint.h>

// ContinuousConvolution, MI355X gfx950. Round 7:
//  - knn v2: cheap conservative tau (16th of per-lane minima via wave bitonic
//    sort-64 of floats), candidates in registers from packed float4 (L2-hot),
//    ballot/mbcnt appends, 1-wave blocks. Exact (d2bits,idx) re-rank unchanged.
//  - mlp: gather reads bf16 copy of pf (halves HBM fetch; error << threshold).
//  - pack kernel builds (x,y,z,sq) float4 + bf16 pf copy.

typedef unsigned short u16;
typedef unsigned int   u32;
typedef unsigned long long u64;

#define NPTS  8192
#define KNB   16
#define SCAP  512   // survivors: E~146, sigma~37 -> +10 sigma
#define QPW   4

__device__ __forceinline__ float bf2f(u16 u) {
    union { u32 i; float f; } v; v.i = ((u32)u) << 16; return v.f;
}
__device__ __forceinline__ u16 f2bf(float f) {
    u32 x = __float_as_uint(f);
    return (u16)((x + 0x7FFFu + ((x >> 16) & 1u)) >> 16);  // RNE
}
__device__ __forceinline__ u32 fordkey(float f) {
    u32 u = __float_as_uint(f);
    return u ^ ((u32)((int)u >> 31) | 0x80000000u);
}
__device__ __forceinline__ u64 shflxor64(u64 v, int m) {
    int lo = __shfl_xor((int)(u32)v, m, 64);
    int hi = __shfl_xor((int)(u32)(v >> 32), m, 64);
    return ((u64)(u32)hi << 32) | (u32)lo;
}
// Reference-matching d2 (verified round 5): dot = Eigen FMA chain, rest strict.
__device__ __forceinline__ float sq_np32(float x, float y, float z) {
    return __fadd_rn(__fadd_rn(__fmul_rn(x, x), __fmul_rn(y, y)), __fmul_rn(z, z));
}
__device__ __forceinline__ float d2_ref(float qx, float qy, float qz, float qsq,
                                        float x, float y, float z, float sq) {
    float dot = fmaf(z, qz, fmaf(y, qy, __fmul_rn(x, qx)));
    return __fsub_rn(__fadd_rn(qsq, sq), __fmul_rn(2.0f, dot));
}

template <int N>
__device__ __forceinline__ void bitonic_sort(u64* k) {
#pragma unroll
    for (int size = 2; size <= N; size <<= 1) {
#pragma unroll
        for (int stride = size >> 1; stride > 0; stride >>= 1) {
#pragma unroll
            for (int i = 0; i < N; ++i) {
                int j = i ^ stride;
                if (j > i) {
                    bool up = ((i & size) == 0);
                    u64 x = k[i], y = k[j];
                    bool sw = up ? (x > y) : (x < y);
                    k[i] = sw ? y : x;
                    k[j] = sw ? x : y;
                }
            }
        }
    }
}

// ---------------- Kernel 0: pack ----------------
// pk[i] = (x,y,z,sq) for all 16384 points; pfh = bf16 copy of pf (1M elems).
__global__ __launch_bounds__(256) void pack_kernel(const float* __restrict__ coords,
                                                   const float* __restrict__ pf,
                                                   float4* __restrict__ pk,
                                                   u16* __restrict__ pfh) {
    int gid = blockIdx.x * 256 + threadIdx.x;       // 0 .. 1048575
    pfh[gid] = f2bf(pf[gid]);
    if (gid < 2 * NPTS) {
        float x = coords[gid * 3 + 0];
        float y = coords[gid * 3 + 1];
        float z = coords[gid * 3 + 2];
        pk[gid] = make_float4(x, y, z, sq_np32(x, y, z));
    }
}

// ---------------- Kernel A: KNN v2 ----------------
// 1 wave per block, 4 queries per wave. grid 4096.
__global__ __launch_bounds__(64, 4) void knn_kernel(const float4* __restrict__ pk,
                                                    int* __restrict__ idx_out) {
    __shared__ u64 surv[4][SCAP];

    const int lane = threadIdx.x;
    const int blk  = blockIdx.x;               // 0..4095
    const int b    = blk >> 11;                // 2048 blocks per batch
    const float4* pkb = pk + b * NPTS;
    const int q0 = (blk & 2047) * 4;

    float4 qc[4];
#pragma unroll
    for (int t = 0; t < 4; ++t) qc[t] = pkb[q0 + t];
    float tauF[4];
    int   cntr[4] = {0, 0, 0, 0};

#pragma unroll 1
    for (int chunk = 0; chunk < 8; ++chunk) {
        float4 c[16];
#pragma unroll
        for (int j = 0; j < 16; ++j) c[j] = pkb[chunk * 1024 + j * 64 + lane];

        if (chunk == 0) {
            // conservative tau per query: 16th-smallest of the 64 lane-minima
#pragma unroll
            for (int t = 0; t < 4; ++t) {
                float dmin = 3.0e38f;
#pragma unroll
                for (int j = 0; j < 16; ++j) {
                    float d2 = d2_ref(qc[t].x, qc[t].y, qc[t].z, qc[t].w,
                                      c[j].x, c[j].y, c[j].z, c[j].w);
                    dmin = fminf(dmin, d2);
                }
                float v = dmin;                 // wave bitonic sort-64, ascending
#pragma unroll
                for (int k = 2; k <= 64; k <<= 1) {
#pragma unroll
                    for (int j2 = k >> 1; j2 >= 1; j2 >>= 1) {
                        float o = __shfl_xor(v, j2, 64);
                        bool lo = (lane & j2) == 0;
                        bool up = (lane & k) == 0;
                        float mn = fminf(v, o), mx = fmaxf(v, o);
                        v = (lo == up) ? mn : mx;
                    }
                }
                tauF[t] = __shfl(v, 15, 64);    // >= sample 16th >= global 16th
            }
        }
        // inclusive filter (covers chunk 0 too); ballot/mbcnt compaction
#pragma unroll
        for (int t = 0; t < 4; ++t) {
            float tF = tauF[t];
#pragma unroll
            for (int j = 0; j < 16; ++j) {
                float d2 = d2_ref(qc[t].x, qc[t].y, qc[t].z, qc[t].w,
                                  c[j].x, c[j].y, c[j].z, c[j].w);
                bool pass = (d2 <= tF);
                u64 mask = __ballot(pass);
                if (pass) {
                    int pre = __builtin_amdgcn_mbcnt_hi((u32)(mask >> 32),
                              __builtin_amdgcn_mbcnt_lo((u32)mask, 0));
                    int pos = cntr[t] + pre;
                    int idx = chunk * 1024 + j * 64 + lane;
                    if (pos < SCAP)
                        surv[t][pos] = ((u64)fordkey(d2) << 32) | (u32)idx;
                }
                cntr[t] += (int)__popcll(mask);
            }
        }
    }
    __syncthreads();   // 1-wave block: cheap; orders LDS writes vs reads

    // phase 3: exact top-16 of survivors by (d2bits, idx)
#pragma unroll 1
    for (int t = 0; t < 4; ++t) {
        int cnt = cntr[t] > SCAP ? SCAP : cntr[t];
        u64 a[8];
#pragma unroll
        for (int j = 0; j < 8; ++j) {
            int p = j * 64 + lane;
            a[j] = (p < cnt) ? surv[t][p] : ~0ull;
        }
        bitonic_sort<8>(a);
        int myidx = 0;
#pragma unroll 1
        for (int r = 0; r < 16; ++r) {
            u64 m = a[0];
#pragma unroll
            for (int d = 1; d < 64; d <<= 1) {
                u64 o = shflxor64(m, d);
                m = (o < m) ? o : m;
            }
            if (a[0] == m) {                    // unique keys: one lane pops
#pragma unroll
                for (int j = 0; j < 7; ++j) a[j] = a[j + 1];
                a[7] = ~0ull;
            }
            if (lane == r) myidx = (int)(u32)(m & 0xffffffffu);
        }
        int gq = b * NPTS + q0 + t;
        if (lane < KNB) idx_out[(size_t)gq * KNB + lane] = myidx;
    }
}

// ---------------- Kernel B: gather + collapsed MLP (bf16 gather) ----------------
__global__ __launch_bounds__(64) void mlp_kernel(
    const u16* __restrict__ pfh, const float* __restrict__ coords,
    const float* __restrict__ w1, const float* __restrict__ b1,
    const float* __restrict__ w2, const float* __restrict__ b2,
    const float* __restrict__ w3, const float* __restrict__ b3,
    const float* __restrict__ aw, const float* __restrict__ ab,
    const int* __restrict__ knn_idx, float* __restrict__ out) {

    __shared__ __attribute__((aligned(16))) float vbuf[2][68];
    __shared__ __attribute__((aligned(16))) float h1buf[2][36];

    const int lane = threadIdx.x;            // 0..63
    const int r    = lane & 31;
    const int vec  = lane >> 5;

    float w1r[68];
#pragma unroll
    for (int c = 0; c < 67; ++c) w1r[c] = w1[r * 67 + c];
    w1r[67] = 0.0f;
    float w2r[32];
    {
        const float4* p = (const float4*)(w2 + lane * 32);
#pragma unroll
        for (int c4 = 0; c4 < 8; ++c4) {
            float4 v = p[c4];
            w2r[c4 * 4 + 0] = v.x; w2r[c4 * 4 + 1] = v.y;
            w2r[c4 * 4 + 2] = v.z; w2r[c4 * 4 + 3] = v.w;
        }
    }
    float w3r[64];
    {
        const float4* p = (const float4*)(w3 + lane * 64);
#pragma unroll
        for (int c4 = 0; c4 < 16; ++c4) {
            float4 v = p[c4];
            w3r[c4 * 4 + 0] = v.x; w3r[c4 * 4 + 1] = v.y;
            w3r[c4 * 4 + 2] = v.z; w3r[c4 * 4 + 3] = v.w;
        }
    }
    float awr[16];
#pragma unroll
    for (int k = 0; k < 16; ++k) awr[k] = aw[k];
    float sa = 0.0f;
#pragma unroll
    for (int k = 0; k < 16; ++k) sa += awr[k];
    const float b1v = b1[r], b2v = b2[lane], b3v = b3[lane], abv = ab[0];
    const float c1 = (vec == 0) ? 16.0f : sa;

#pragma unroll 1
    for (int t = 0; t < QPW; ++t) {
        const int gq = blockIdx.x * QPW + t;
        const int b  = gq >> 13;
        const u16*   pfb = pfh + (size_t)b * NPTS * 64;
        const float* cb  = coords + (size_t)b * NPTS * 3;

        int myi = knn_idx[(size_t)gq * KNB + (lane & 15)] & (NPTS - 1);

        float pool = -3.0e38f, G1 = 0.0f, Ga = 0.0f;
#pragma unroll
        for (int k = 0; k < 16; ++k) {
            int nk = __shfl(myi, k, 64);
            float v = bf2f(pfb[nk * 64 + lane]);
            pool = fmaxf(pool, v);
            G1 += v;
            Ga = fmaf(awr[k], v, Ga);
        }
        vbuf[0][lane] = G1;
        vbuf[1][lane] = Ga;

        if (lane < 48) {
            int j  = lane >> 4;
            int i0 = __shfl(myi, 0, 64);
            float rel  = cb[myi * 3 + j] - cb[i0 * 3 + j];
            float wrel = awr[lane & 15] * rel;
#pragma unroll
            for (int d = 1; d < 16; d <<= 1) {
                rel  += __shfl_xor(rel, d, 64);
                wrel += __shfl_xor(wrel, d, 64);
            }
            if ((lane & 15) == 0) { vbuf[0][64 + j] = rel; vbuf[1][64 + j] = wrel; }
        }
        if (lane == 0) { vbuf[0][67] = 0.0f; vbuf[1][67] = 0.0f; }
        __syncthreads();

        float acc = c1 * b1v;
        {
            const float4* vp = (const float4*)(&vbuf[vec][0]);
#pragma unroll
            for (int c4 = 0; c4 < 17; ++c4) {
                float4 g4 = vp[c4];
                acc = fmaf(g4.x, w1r[c4 * 4 + 0], acc);
                acc = fmaf(g4.y, w1r[c4 * 4 + 1], acc);
                acc = fmaf(g4.z, w1r[c4 * 4 + 2], acc);
                acc = fmaf(g4.w, w1r[c4 * 4 + 3], acc);
            }
        }
        h1buf[vec][r] = acc;
        __syncthreads();

        float a0 = 16.0f * b2v, a1 = sa * b2v;
        {
            const float4* p0 = (const float4*)(&h1buf[0][0]);
            const float4* p1 = (const float4*)(&h1buf[1][0]);
#pragma unroll
            for (int c4 = 0; c4 < 8; ++c4) {
                float4 x0 = p0[c4], x1 = p1[c4];
                a0 = fmaf(x0.x, w2r[c4 * 4 + 0], a0);
                a0 = fmaf(x0.y, w2r[c4 * 4 + 1], a0);
                a0 = fmaf(x0.z, w2r[c4 * 4 + 2], a0);
                a0 = fmaf(x0.w, w2r[c4 * 4 + 3], a0);
                a1 = fmaf(x1.x, w2r[c4 * 4 + 0], a1);
                a1 = fmaf(x1.y, w2r[c4 * 4 + 1], a1);
                a1 = fmaf(x1.z, w2r[c4 * 4 + 2], a1);
                a1 = fmaf(x1.w, w2r[c4 * 4 + 3], a1);
            }
        }
        __syncthreads();
        vbuf[0][lane] = a0;
        vbuf[1][lane] = a1;
        __syncthreads();

        float s1 = 16.0f * b3v, sA = sa * b3v;
        {
            const float4* p0 = (const float4*)(&vbuf[0][0]);
            const float4* p1 = (const float4*)(&vbuf[1][0]);
#pragma unroll
            for (int c4 = 0; c4 < 16; ++c4) {
                float4 x0 = p0[c4], x1 = p1[c4];
                s1 = fmaf(x0.x, w3r[c4 * 4 + 0], s1);
                s1 = fmaf(x0.y, w3r[c4 * 4 + 1], s1);
                s1 = fmaf(x0.z, w3r[c4 * 4 + 2], s1);
                s1 = fmaf(x0.w, w3r[c4 * 4 + 3], s1);
                sA = fmaf(x1.x, w3r[c4 * 4 + 0], sA);
                sA = fmaf(x1.y, w3r[c4 * 4 + 1], sA);
                sA = fmaf(x1.z, w3r[c4 * 4 + 2], sA);
                sA = fmaf(x1.w, w3r[c4 * 4 + 3], sA);
            }
        }
        float* op = out + (size_t)gq * 192;
        op[lane]       = s1;
        op[64 + lane]  = pool;
        op[128 + lane] = sA + abv;
        __syncthreads();
    }
}

extern "C" void kernel_launch(void* const* d_in, const int* in_sizes, int n_in,
                              void* d_out, int out_size, void* d_ws, size_t ws_size,
                              hipStream_t stream) {
    const float* pf     = (const float*)d_in[0];
    const float* coords = (const float*)d_in[1];
    const float* w1     = (const float*)d_in[2];
    const float* b1     = (const float*)d_in[3];
    const float* w2     = (const float*)d_in[4];
    const float* b2     = (const float*)d_in[5];
    const float* w3     = (const float*)d_in[6];
    const float* b3     = (const float*)d_in[7];
    const float* aw     = (const float*)d_in[8];
    const float* ab     = (const float*)d_in[9];

    char* ws = (char*)d_ws;
    int*    knn_idx = (int*)ws;                         // 1 MB
    float4* pk      = (float4*)(ws + (1 << 20));        // 256 KB
    u16*    pfh     = (u16*)(ws + (1 << 20) + (256 << 10)); // 2 MB
    float*  outp    = (float*)d_out;

    pack_kernel<<<4096, 256, 0, stream>>>(coords, pf, pk, pfh);
    knn_kernel<<<4096, 64, 0, stream>>>(pk, knn_idx);
    mlp_kernel<<<4096, 64, 0, stream>>>(pfh, coords, w1, b1, w2, b2, w3, b3,
                                        aw, ab, knn_idx, outp);
}

// Round 9
// 153.593 us; speedup vs baseline: 3.6988x; 1.6187x over previous
//
#include <hip/hip_runtime.h>
#include <stdint.h>

// ContinuousConvolution, MI355X gfx950. Round 9: fix R8's wave-divergence bug.
// R8's variable-length cell-range loops had per-lane trip counts, breaking the
// ballot/mbcnt compaction (cnt diverged across lanes -> corrupted survivors).
// All scan loops are now wave-uniform: uniform bounds, lane-derived index,
// validity mask folded into the ballot predicate. Algorithm otherwise as R8:
//  - 8x8x8 cell grid per batch; tau = 16th of 64 lane-minima over 3^3 box
//    (provable upper bound); search cells within r = sqrt(tau+1e-5);
//    filter d2<=tau; exact top-16 by (d2bits, orig idx).
//  - d2 expression = R5-verified reference match (Eigen FMA dot, strict rest).
//  - mlp: collapsed-linear, lossless bf16 gather, QPW=8.

typedef unsigned short u16;
typedef unsigned int   u32;
typedef unsigned long long u64;

#define NPTS  8192
#define KNB   16
#define SCAP  128   // survivors: E~20, n-independent
#define QPW   8

__device__ __forceinline__ float bf2f(u16 u) {
    union { u32 i; float f; } v; v.i = ((u32)u) << 16; return v.f;
}
__device__ __forceinline__ u16 f2bf(float f) {
    u32 x = __float_as_uint(f);
    return (u16)((x + 0x7FFFu + ((x >> 16) & 1u)) >> 16);  // RNE (lossless here)
}
__device__ __forceinline__ u32 fordkey(float f) {
    u32 u = __float_as_uint(f);
    return u ^ ((u32)((int)u >> 31) | 0x80000000u);
}
__device__ __forceinline__ u64 shflxor64(u64 v, int m) {
    int lo = __shfl_xor((int)(u32)v, m, 64);
    int hi = __shfl_xor((int)(u32)(v >> 32), m, 64);
    return ((u64)(u32)hi << 32) | (u32)lo;
}
// Reference-matching d2 (verified round 5): dot = Eigen FMA chain, rest strict.
__device__ __forceinline__ float sq_np32(float x, float y, float z) {
    return __fadd_rn(__fadd_rn(__fmul_rn(x, x), __fmul_rn(y, y)), __fmul_rn(z, z));
}
__device__ __forceinline__ float d2_ref(float qx, float qy, float qz, float qsq,
                                        float x, float y, float z, float sq) {
    float dot = fmaf(z, qz, fmaf(y, qy, __fmul_rn(x, qx)));
    return __fsub_rn(__fadd_rn(qsq, sq), __fmul_rn(2.0f, dot));
}
__device__ __forceinline__ int cellof(float v) {
    int c = (int)floorf(v * 8.0f);
    return c < 0 ? 0 : (c > 7 ? 7 : c);
}

// ---------------- build kernels ----------------
__global__ __launch_bounds__(256) void pack_count_kernel(
    const float* __restrict__ pf, const float* __restrict__ coords,
    u16* __restrict__ pfh, int* __restrict__ counts) {
    int gid = blockIdx.x * 256 + threadIdx.x;     // 0..1048575
    pfh[gid] = f2bf(pf[gid]);
    if (gid < 2 * NPTS) {
        float x = coords[gid * 3 + 0];
        float y = coords[gid * 3 + 1];
        float z = coords[gid * 3 + 2];
        int b = gid >> 13;
        int cell = (cellof(x) * 8 + cellof(y)) * 8 + cellof(z);
        atomicAdd(&counts[b * 512 + cell], 1);
    }
}

__global__ __launch_bounds__(512) void scan_kernel(
    const int* __restrict__ counts, int* __restrict__ cellStart,
    int* __restrict__ cellOffset) {
    __shared__ int s[512];
    int b = blockIdx.x, t = threadIdx.x;
    int myc = counts[b * 512 + t];
    s[t] = myc; __syncthreads();
#pragma unroll
    for (int off = 1; off < 512; off <<= 1) {
        int v = (t >= off) ? s[t - off] : 0; __syncthreads();
        s[t] += v; __syncthreads();
    }
    int excl = s[t] - myc;
    cellStart[b * 513 + t] = excl;
    cellOffset[b * 512 + t] = excl;
    if (t == 511) cellStart[b * 513 + 512] = s[511];
}

__global__ __launch_bounds__(256) void scatter_kernel(
    const float* __restrict__ coords, int* __restrict__ cellOffset,
    float4* __restrict__ spts, int* __restrict__ sidx) {
    int gid = blockIdx.x * 256 + threadIdx.x;     // 0..16383
    float x = coords[gid * 3 + 0];
    float y = coords[gid * 3 + 1];
    float z = coords[gid * 3 + 2];
    int b = gid >> 13, i = gid & (NPTS - 1);
    int cell = (cellof(x) * 8 + cellof(y)) * 8 + cellof(z);
    int pos = atomicAdd(&cellOffset[b * 512 + cell], 1);
    spts[b * NPTS + pos] = make_float4(x, y, z, sq_np32(x, y, z));
    sidx[b * NPTS + pos] = i;
}

// ---------------- Kernel A: grid knn ----------------
// 1 wave per block, 4 queries per wave. grid 4096.
__global__ __launch_bounds__(64, 4) void knn_kernel(
    const float* __restrict__ coords, const float4* __restrict__ spts,
    const int* __restrict__ sidx, const int* __restrict__ cellStart,
    int* __restrict__ idx_out) {
    __shared__ u64 surv[SCAP];

    const int lane = threadIdx.x;
    const int blk  = blockIdx.x;               // 0..4095
    const int b    = blk >> 11;
    const int q0   = (blk & 2047) * 4;
    const float*  cb = coords + (size_t)b * NPTS * 3;
    const float4* sp = spts + b * NPTS;
    const int*    si = sidx + b * NPTS;
    const int*    cs = cellStart + b * 513;

#pragma unroll 1
    for (int t = 0; t < 4; ++t) {
        const int q = q0 + t;
        float qx = cb[q * 3 + 0], qy = cb[q * 3 + 1], qz = cb[q * 3 + 2];
        float qsq = sq_np32(qx, qy, qz);
        int cqx = cellof(qx), cqy = cellof(qy), cqz = cellof(qz);

        // PASS A: lane-minima over the 3x3x3 cell box -> conservative tau.
        // WAVE-UNIFORM loops: uniform bounds, lane-derived index, masked min.
        int ax0 = max(cqx - 1, 0), ax1 = min(cqx + 1, 7);
        int ay0 = max(cqy - 1, 0), ay1 = min(cqy + 1, 7);
        int az0 = max(cqz - 1, 0), az1 = min(cqz + 1, 7);
        float dmin = 3.0e38f;
#pragma unroll 1
        for (int cx = ax0; cx <= ax1; ++cx)
#pragma unroll 1
            for (int cy = ay0; cy <= ay1; ++cy) {
                int base = (cx * 8 + cy) * 8;
                int s = cs[base + az0], e = cs[base + az1 + 1];
                for (int i0 = s; i0 < e; i0 += 64) {
                    int i = i0 + lane;
                    int ii = (i < e) ? i : (e - 1);     // clamp: no OOB
                    float4 c = sp[ii];
                    float d2 = d2_ref(qx, qy, qz, qsq, c.x, c.y, c.z, c.w);
                    if (i < e) dmin = fminf(dmin, d2);
                }
            }
        {   // wave bitonic sort-64 ascending
            float v = dmin;
#pragma unroll
            for (int k = 2; k <= 64; k <<= 1) {
#pragma unroll
                for (int j2 = k >> 1; j2 >= 1; j2 >>= 1) {
                    float o = __shfl_xor(v, j2, 64);
                    bool lo = (lane & j2) == 0;
                    bool up = (lane & k) == 0;
                    float mn = fminf(v, o), mx = fmaxf(v, o);
                    v = (lo == up) ? mn : mx;
                }
            }
            dmin = __shfl(v, 15, 64);          // 16th smallest lane-min
        }
        const float tau = dmin;                 // >= true 16th-NN d2

        // PASS B: search cells within r; filter d2 <= tau.
        // WAVE-UNIFORM loop so ballot/popcount keep cnt uniform (R8 bugfix).
        float rr = sqrtf(tau + 1e-5f) + 1e-6f;
        int bx0 = max((int)floorf((qx - rr) * 8.0f), 0);
        int bx1 = min((int)floorf((qx + rr) * 8.0f), 7);
        int by0 = max((int)floorf((qy - rr) * 8.0f), 0);
        int by1 = min((int)floorf((qy + rr) * 8.0f), 7);
        int bz0 = max((int)floorf((qz - rr) * 8.0f), 0);
        int bz1 = min((int)floorf((qz + rr) * 8.0f), 7);
        int cnt = 0;
#pragma unroll 1
        for (int cx = bx0; cx <= bx1; ++cx)
#pragma unroll 1
            for (int cy = by0; cy <= by1; ++cy) {
                int base = (cx * 8 + cy) * 8;
                int s = cs[base + bz0], e = cs[base + bz1 + 1];
                for (int i0 = s; i0 < e; i0 += 64) {
                    int i = i0 + lane;
                    bool valid = (i < e);
                    int ii = valid ? i : (e - 1);       // clamp: no OOB
                    float4 c = sp[ii];
                    float d2 = d2_ref(qx, qy, qz, qsq, c.x, c.y, c.z, c.w);
                    bool pass = valid && (d2 <= tau);
                    u64 mask = __ballot(pass);
                    if (pass) {
                        int pre = __builtin_amdgcn_mbcnt_hi((u32)(mask >> 32),
                                  __builtin_amdgcn_mbcnt_lo((u32)mask, 0));
                        int pos = cnt + pre;
                        if (pos < SCAP)
                            surv[pos] = ((u64)fordkey(d2) << 32) | (u32)si[ii];
                    }
                    cnt += (int)__popcll(mask);         // uniform across wave
                }
            }
        __syncthreads();   // 1-wave: cheap; orders LDS writes vs reads

        int myidx = 0;
        if (cnt <= 64) {
            // common path: one wave bitonic sort-64 of u64 (d2bits, idx) keys
            u64 key = (lane < cnt) ? surv[lane] : ~0ull;
#pragma unroll
            for (int k = 2; k <= 64; k <<= 1) {
#pragma unroll
                for (int j2 = k >> 1; j2 >= 1; j2 >>= 1) {
                    u64 o = shflxor64(key, j2);
                    bool lo = (lane & j2) == 0;
                    bool up = (lane & k) == 0;
                    bool takemin = (lo == up);
                    key = ((o < key) == takemin) ? o : key;
                }
            }
            myidx = (int)(u32)(key & 0xffffffffu);  // lanes 0..15 = top-16 asc
        } else {
            // rare fallback: extraction over up to SCAP survivors
            int cc = cnt > SCAP ? SCAP : cnt;
            u64 a0 = (lane < cc) ? surv[lane] : ~0ull;
            u64 a1 = (64 + lane < cc) ? surv[64 + lane] : ~0ull;
            if (a1 < a0) { u64 tmp = a0; a0 = a1; a1 = tmp; }
#pragma unroll 1
            for (int r = 0; r < 16; ++r) {
                u64 m = a0;
#pragma unroll
                for (int d = 1; d < 64; d <<= 1) {
                    u64 o = shflxor64(m, d);
                    m = (o < m) ? o : m;
                }
                if (a0 == m) { a0 = a1; a1 = ~0ull; }
                if (lane == r) myidx = (int)(u32)(m & 0xffffffffu);
            }
        }
        if (lane < KNB)
            idx_out[((size_t)b * NPTS + q) * KNB + lane] = myidx;
        __syncthreads();   // before next query overwrites surv
    }
}

// ---------------- Kernel B: gather + collapsed MLP (bf16 gather) ----------------
__global__ __launch_bounds__(64) void mlp_kernel(
    const u16* __restrict__ pfh, const float* __restrict__ coords,
    const float* __restrict__ w1, const float* __restrict__ b1,
    const float* __restrict__ w2, const float* __restrict__ b2,
    const float* __restrict__ w3, const float* __restrict__ b3,
    const float* __restrict__ aw, const float* __restrict__ ab,
    const int* __restrict__ knn_idx, float* __restrict__ out) {

    __shared__ __attribute__((aligned(16))) float vbuf[2][68];
    __shared__ __attribute__((aligned(16))) float h1buf[2][36];

    const int lane = threadIdx.x;            // 0..63
    const int r    = lane & 31;
    const int vec  = lane >> 5;

    float w1r[68];
#pragma unroll
    for (int c = 0; c < 67; ++c) w1r[c] = w1[r * 67 + c];
    w1r[67] = 0.0f;
    float w2r[32];
    {
        const float4* p = (const float4*)(w2 + lane * 32);
#pragma unroll
        for (int c4 = 0; c4 < 8; ++c4) {
            float4 v = p[c4];
            w2r[c4 * 4 + 0] = v.x; w2r[c4 * 4 + 1] = v.y;
            w2r[c4 * 4 + 2] = v.z; w2r[c4 * 4 + 3] = v.w;
        }
    }
    float w3r[64];
    {
        const float4* p = (const float4*)(w3 + lane * 64);
#pragma unroll
        for (int c4 = 0; c4 < 16; ++c4) {
            float4 v = p[c4];
            w3r[c4 * 4 + 0] = v.x; w3r[c4 * 4 + 1] = v.y;
            w3r[c4 * 4 + 2] = v.z; w3r[c4 * 4 + 3] = v.w;
        }
    }
    float awr[16];
#pragma unroll
    for (int k = 0; k < 16; ++k) awr[k] = aw[k];
    float sa = 0.0f;
#pragma unroll
    for (int k = 0; k < 16; ++k) sa += awr[k];
    const float b1v = b1[r], b2v = b2[lane], b3v = b3[lane], abv = ab[0];
    const float c1 = (vec == 0) ? 16.0f : sa;

#pragma unroll 1
    for (int t = 0; t < QPW; ++t) {
        const int gq = blockIdx.x * QPW + t;
        const int b  = gq >> 13;
        const u16*   pfb = pfh + (size_t)b * NPTS * 64;
        const float* cb  = coords + (size_t)b * NPTS * 3;

        int myi = knn_idx[(size_t)gq * KNB + (lane & 15)] & (NPTS - 1);

        float pool = -3.0e38f, G1 = 0.0f, Ga = 0.0f;
#pragma unroll
        for (int k = 0; k < 16; ++k) {
            int nk = __shfl(myi, k, 64);
            float v = bf2f(pfb[nk * 64 + lane]);
            pool = fmaxf(pool, v);
            G1 += v;
            Ga = fmaf(awr[k], v, Ga);
        }
        vbuf[0][lane] = G1;
        vbuf[1][lane] = Ga;

        if (lane < 48) {
            int j  = lane >> 4;
            int i0 = __shfl(myi, 0, 64);
            float rel  = cb[myi * 3 + j] - cb[i0 * 3 + j];
            float wrel = awr[lane & 15] * rel;
#pragma unroll
            for (int d = 1; d < 16; d <<= 1) {
                rel  += __shfl_xor(rel, d, 64);
                wrel += __shfl_xor(wrel, d, 64);
            }
            if ((lane & 15) == 0) { vbuf[0][64 + j] = rel; vbuf[1][64 + j] = wrel; }
        }
        if (lane == 0) { vbuf[0][67] = 0.0f; vbuf[1][67] = 0.0f; }
        __syncthreads();

        float acc = c1 * b1v;
        {
            const float4* vp = (const float4*)(&vbuf[vec][0]);
#pragma unroll
            for (int c4 = 0; c4 < 17; ++c4) {
                float4 g4 = vp[c4];
                acc = fmaf(g4.x, w1r[c4 * 4 + 0], acc);
                acc = fmaf(g4.y, w1r[c4 * 4 + 1], acc);
                acc = fmaf(g4.z, w1r[c4 * 4 + 2], acc);
                acc = fmaf(g4.w, w1r[c4 * 4 + 3], acc);
            }
        }
        h1buf[vec][r] = acc;
        __syncthreads();

        float a0 = 16.0f * b2v, a1 = sa * b2v;
        {
            const float4* p0 = (const float4*)(&h1buf[0][0]);
            const float4* p1 = (const float4*)(&h1buf[1][0]);
#pragma unroll
            for (int c4 = 0; c4 < 8; ++c4) {
                float4 x0 = p0[c4], x1 = p1[c4];
                a0 = fmaf(x0.x, w2r[c4 * 4 + 0], a0);
                a0 = fmaf(x0.y, w2r[c4 * 4 + 1], a0);
                a0 = fmaf(x0.z, w2r[c4 * 4 + 2], a0);
                a0 = fmaf(x0.w, w2r[c4 * 4 + 3], a0);
                a1 = fmaf(x1.x, w2r[c4 * 4 + 0], a1);
                a1 = fmaf(x1.y, w2r[c4 * 4 + 1], a1);
                a1 = fmaf(x1.z, w2r[c4 * 4 + 2], a1);
                a1 = fmaf(x1.w, w2r[c4 * 4 + 3], a1);
            }
        }
        __syncthreads();
        vbuf[0][lane] = a0;
        vbuf[1][lane] = a1;
        __syncthreads();

        float s1 = 16.0f * b3v, sA = sa * b3v;
        {
            const float4* p0 = (const float4*)(&vbuf[0][0]);
            const float4* p1 = (const float4*)(&vbuf[1][0]);
#pragma unroll
            for (int c4 = 0; c4 < 16; ++c4) {
                float4 x0 = p0[c4], x1 = p1[c4];
                s1 = fmaf(x0.x, w3r[c4 * 4 + 0], s1);
                s1 = fmaf(x0.y, w3r[c4 * 4 + 1], s1);
                s1 = fmaf(x0.z, w3r[c4 * 4 + 2], s1);
                s1 = fmaf(x0.w, w3r[c4 * 4 + 3], s1);
                sA = fmaf(x1.x, w3r[c4 * 4 + 0], sA);
                sA = fmaf(x1.y, w3r[c4 * 4 + 1], sA);
                sA = fmaf(x1.z, w3r[c4 * 4 + 2], sA);
                sA = fmaf(x1.w, w3r[c4 * 4 + 3], sA);
            }
        }
        float* op = out + (size_t)gq * 192;
        op[lane]       = s1;
        op[64 + lane]  = pool;
        op[128 + lane] = sA + abv;
        __syncthreads();
    }
}

extern "C" void kernel_launch(void* const* d_in, const int* in_sizes, int n_in,
                              void* d_out, int out_size, void* d_ws, size_t ws_size,
                              hipStream_t stream) {
    const float* pf     = (const float*)d_in[0];
    const float* coords = (const float*)d_in[1];
    const float* w1     = (const float*)d_in[2];
    const float* b1     = (const float*)d_in[3];
    const float* w2     = (const float*)d_in[4];
    const float* b2     = (const float*)d_in[5];
    const float* w3     = (const float*)d_in[6];
    const float* b3     = (const float*)d_in[7];
    const float* aw     = (const float*)d_in[8];
    const float* ab     = (const float*)d_in[9];

    char* ws = (char*)d_ws;
    int*    knn_idx    = (int*)ws;                              // 1 MB
    u16*    pfh        = (u16*)(ws + (1 << 20));                // 2 MB
    float4* spts       = (float4*)(ws + (3 << 20));             // 256 KB
    int*    sidx       = (int*)(ws + (3 << 20) + (256 << 10));  // 64 KB
    int*    cellStart  = (int*)(ws + (3 << 20) + (320 << 10));  // 2*513*4 B
    int*    counts     = (int*)(ws + (3 << 20) + (328 << 10));  // 2*512*4 B
    int*    cellOffset = (int*)(ws + (3 << 20) + (336 << 10));  // 2*512*4 B
    float*  outp       = (float*)d_out;

    hipMemsetAsync(counts, 0, 2 * 512 * sizeof(int), stream);
    pack_count_kernel<<<4096, 256, 0, stream>>>(pf, coords, pfh, counts);
    scan_kernel<<<2, 512, 0, stream>>>(counts, cellStart, cellOffset);
    scatter_kernel<<<64, 256, 0, stream>>>(coords, cellOffset, spts, sidx);
    knn_kernel<<<4096, 64, 0, stream>>>(coords, spts, sidx, cellStart, knn_idx);
    mlp_kernel<<<2048, 64, 0, stream>>>(pfh, coords, w1, b1, w2, b2, w3, b3,
                                        aw, ab, knn_idx, outp);
}

// Round 10
// 151.774 us; speedup vs baseline: 3.7432x; 1.0120x over previous
//
#include <hip/hip_runtime.h>
#include <stdint.h>

// ContinuousConvolution, MI355X gfx950. Round 10: mlp processes queries in
// sorted grid-cell order with XCD-chunk swizzle -> neighbor-row gathers become
// per-XCD L2 hits (useful pfh traffic ~4 MB instead of ~250 MB re-fetch).
// KNN + builds identical to R9 (verified exact). Output bit-identical to R9.

typedef unsigned short u16;
typedef unsigned int   u32;
typedef unsigned long long u64;

#define NPTS  8192
#define KNB   16
#define SCAP  128   // survivors: E~20, n-independent
#define QPW   8

__device__ __forceinline__ float bf2f(u16 u) {
    union { u32 i; float f; } v; v.i = ((u32)u) << 16; return v.f;
}
__device__ __forceinline__ u16 f2bf(float f) {
    u32 x = __float_as_uint(f);
    return (u16)((x + 0x7FFFu + ((x >> 16) & 1u)) >> 16);  // RNE (lossless here)
}
__device__ __forceinline__ u32 fordkey(float f) {
    u32 u = __float_as_uint(f);
    return u ^ ((u32)((int)u >> 31) | 0x80000000u);
}
__device__ __forceinline__ u64 shflxor64(u64 v, int m) {
    int lo = __shfl_xor((int)(u32)v, m, 64);
    int hi = __shfl_xor((int)(u32)(v >> 32), m, 64);
    return ((u64)(u32)hi << 32) | (u32)lo;
}
// Reference-matching d2 (verified round 5): dot = Eigen FMA chain, rest strict.
__device__ __forceinline__ float sq_np32(float x, float y, float z) {
    return __fadd_rn(__fadd_rn(__fmul_rn(x, x), __fmul_rn(y, y)), __fmul_rn(z, z));
}
__device__ __forceinline__ float d2_ref(float qx, float qy, float qz, float qsq,
                                        float x, float y, float z, float sq) {
    float dot = fmaf(z, qz, fmaf(y, qy, __fmul_rn(x, qx)));
    return __fsub_rn(__fadd_rn(qsq, sq), __fmul_rn(2.0f, dot));
}
__device__ __forceinline__ int cellof(float v) {
    int c = (int)floorf(v * 8.0f);
    return c < 0 ? 0 : (c > 7 ? 7 : c);
}

// ---------------- build kernels ----------------
__global__ __launch_bounds__(256) void pack_count_kernel(
    const float* __restrict__ pf, const float* __restrict__ coords,
    u16* __restrict__ pfh, int* __restrict__ counts) {
    int gid = blockIdx.x * 256 + threadIdx.x;     // 0..1048575
    pfh[gid] = f2bf(pf[gid]);
    if (gid < 2 * NPTS) {
        float x = coords[gid * 3 + 0];
        float y = coords[gid * 3 + 1];
        float z = coords[gid * 3 + 2];
        int b = gid >> 13;
        int cell = (cellof(x) * 8 + cellof(y)) * 8 + cellof(z);
        atomicAdd(&counts[b * 512 + cell], 1);
    }
}

__global__ __launch_bounds__(512) void scan_kernel(
    const int* __restrict__ counts, int* __restrict__ cellStart,
    int* __restrict__ cellOffset) {
    __shared__ int s[512];
    int b = blockIdx.x, t = threadIdx.x;
    int myc = counts[b * 512 + t];
    s[t] = myc; __syncthreads();
#pragma unroll
    for (int off = 1; off < 512; off <<= 1) {
        int v = (t >= off) ? s[t - off] : 0; __syncthreads();
        s[t] += v; __syncthreads();
    }
    int excl = s[t] - myc;
    cellStart[b * 513 + t] = excl;
    cellOffset[b * 512 + t] = excl;
    if (t == 511) cellStart[b * 513 + 512] = s[511];
}

__global__ __launch_bounds__(256) void scatter_kernel(
    const float* __restrict__ coords, int* __restrict__ cellOffset,
    float4* __restrict__ spts, int* __restrict__ sidx) {
    int gid = blockIdx.x * 256 + threadIdx.x;     // 0..16383
    float x = coords[gid * 3 + 0];
    float y = coords[gid * 3 + 1];
    float z = coords[gid * 3 + 2];
    int b = gid >> 13, i = gid & (NPTS - 1);
    int cell = (cellof(x) * 8 + cellof(y)) * 8 + cellof(z);
    int pos = atomicAdd(&cellOffset[b * 512 + cell], 1);
    spts[b * NPTS + pos] = make_float4(x, y, z, sq_np32(x, y, z));
    sidx[b * NPTS + pos] = i;
}

// ---------------- Kernel A: grid knn (unchanged from R9) ----------------
__global__ __launch_bounds__(64, 4) void knn_kernel(
    const float* __restrict__ coords, const float4* __restrict__ spts,
    const int* __restrict__ sidx, const int* __restrict__ cellStart,
    int* __restrict__ idx_out) {
    __shared__ u64 surv[SCAP];

    const int lane = threadIdx.x;
    const int blk  = blockIdx.x;               // 0..4095
    const int b    = blk >> 11;
    const int q0   = (blk & 2047) * 4;
    const float*  cb = coords + (size_t)b * NPTS * 3;
    const float4* sp = spts + b * NPTS;
    const int*    si = sidx + b * NPTS;
    const int*    cs = cellStart + b * 513;

#pragma unroll 1
    for (int t = 0; t < 4; ++t) {
        const int q = q0 + t;
        float qx = cb[q * 3 + 0], qy = cb[q * 3 + 1], qz = cb[q * 3 + 2];
        float qsq = sq_np32(qx, qy, qz);
        int cqx = cellof(qx), cqy = cellof(qy), cqz = cellof(qz);

        // PASS A: lane-minima over the 3x3x3 cell box -> conservative tau.
        int ax0 = max(cqx - 1, 0), ax1 = min(cqx + 1, 7);
        int ay0 = max(cqy - 1, 0), ay1 = min(cqy + 1, 7);
        int az0 = max(cqz - 1, 0), az1 = min(cqz + 1, 7);
        float dmin = 3.0e38f;
#pragma unroll 1
        for (int cx = ax0; cx <= ax1; ++cx)
#pragma unroll 1
            for (int cy = ay0; cy <= ay1; ++cy) {
                int base = (cx * 8 + cy) * 8;
                int s = cs[base + az0], e = cs[base + az1 + 1];
                for (int i0 = s; i0 < e; i0 += 64) {
                    int i = i0 + lane;
                    int ii = (i < e) ? i : (e - 1);     // clamp: no OOB
                    float4 c = sp[ii];
                    float d2 = d2_ref(qx, qy, qz, qsq, c.x, c.y, c.z, c.w);
                    if (i < e) dmin = fminf(dmin, d2);
                }
            }
        {   // wave bitonic sort-64 ascending
            float v = dmin;
#pragma unroll
            for (int k = 2; k <= 64; k <<= 1) {
#pragma unroll
                for (int j2 = k >> 1; j2 >= 1; j2 >>= 1) {
                    float o = __shfl_xor(v, j2, 64);
                    bool lo = (lane & j2) == 0;
                    bool up = (lane & k) == 0;
                    float mn = fminf(v, o), mx = fmaxf(v, o);
                    v = (lo == up) ? mn : mx;
                }
            }
            dmin = __shfl(v, 15, 64);          // 16th smallest lane-min
        }
        const float tau = dmin;                 // >= true 16th-NN d2

        // PASS B: search cells within r; filter d2 <= tau (wave-uniform loops).
        float rr = sqrtf(tau + 1e-5f) + 1e-6f;
        int bx0 = max((int)floorf((qx - rr) * 8.0f), 0);
        int bx1 = min((int)floorf((qx + rr) * 8.0f), 7);
        int by0 = max((int)floorf((qy - rr) * 8.0f), 0);
        int by1 = min((int)floorf((qy + rr) * 8.0f), 7);
        int bz0 = max((int)floorf((qz - rr) * 8.0f), 0);
        int bz1 = min((int)floorf((qz + rr) * 8.0f), 7);
        int cnt = 0;
#pragma unroll 1
        for (int cx = bx0; cx <= bx1; ++cx)
#pragma unroll 1
            for (int cy = by0; cy <= by1; ++cy) {
                int base = (cx * 8 + cy) * 8;
                int s = cs[base + bz0], e = cs[base + bz1 + 1];
                for (int i0 = s; i0 < e; i0 += 64) {
                    int i = i0 + lane;
                    bool valid = (i < e);
                    int ii = valid ? i : (e - 1);       // clamp: no OOB
                    float4 c = sp[ii];
                    float d2 = d2_ref(qx, qy, qz, qsq, c.x, c.y, c.z, c.w);
                    bool pass = valid && (d2 <= tau);
                    u64 mask = __ballot(pass);
                    if (pass) {
                        int pre = __builtin_amdgcn_mbcnt_hi((u32)(mask >> 32),
                                  __builtin_amdgcn_mbcnt_lo((u32)mask, 0));
                        int pos = cnt + pre;
                        if (pos < SCAP)
                            surv[pos] = ((u64)fordkey(d2) << 32) | (u32)si[ii];
                    }
                    cnt += (int)__popcll(mask);         // uniform across wave
                }
            }
        __syncthreads();

        int myidx = 0;
        if (cnt <= 64) {
            u64 key = (lane < cnt) ? surv[lane] : ~0ull;
#pragma unroll
            for (int k = 2; k <= 64; k <<= 1) {
#pragma unroll
                for (int j2 = k >> 1; j2 >= 1; j2 >>= 1) {
                    u64 o = shflxor64(key, j2);
                    bool lo = (lane & j2) == 0;
                    bool up = (lane & k) == 0;
                    bool takemin = (lo == up);
                    key = ((o < key) == takemin) ? o : key;
                }
            }
            myidx = (int)(u32)(key & 0xffffffffu);  // lanes 0..15 = top-16 asc
        } else {
            int cc = cnt > SCAP ? SCAP : cnt;
            u64 a0 = (lane < cc) ? surv[lane] : ~0ull;
            u64 a1 = (64 + lane < cc) ? surv[64 + lane] : ~0ull;
            if (a1 < a0) { u64 tmp = a0; a0 = a1; a1 = tmp; }
#pragma unroll 1
            for (int r = 0; r < 16; ++r) {
                u64 m = a0;
#pragma unroll
                for (int d = 1; d < 64; d <<= 1) {
                    u64 o = shflxor64(m, d);
                    m = (o < m) ? o : m;
                }
                if (a0 == m) { a0 = a1; a1 = ~0ull; }
                if (lane == r) myidx = (int)(u32)(m & 0xffffffffu);
            }
        }
        if (lane < KNB)
            idx_out[((size_t)b * NPTS + q) * KNB + lane] = myidx;
        __syncthreads();
    }
}

// ---------------- Kernel B: gather + collapsed MLP, sorted order ----------------
// grid 2048 (= 8 XCD chunks x 256). Swizzle: hardware round-robins blk%8 -> XCD,
// so sblk = (blk&7)*256 + blk>>3 gives each XCD a CONTIGUOUS sorted-query chunk
// -> neighbor gathers hit that XCD's L2 (working set ~0.5 MB + halo << 4 MB).
__global__ __launch_bounds__(64) void mlp_kernel(
    const u16* __restrict__ pfh, const float* __restrict__ coords,
    const float* __restrict__ w1, const float* __restrict__ b1,
    const float* __restrict__ w2, const float* __restrict__ b2,
    const float* __restrict__ w3, const float* __restrict__ b3,
    const float* __restrict__ aw, const float* __restrict__ ab,
    const int* __restrict__ knn_idx, const int* __restrict__ sidx,
    float* __restrict__ out) {

    __shared__ __attribute__((aligned(16))) float vbuf[2][68];
    __shared__ __attribute__((aligned(16))) float h1buf[2][36];

    const int lane = threadIdx.x;            // 0..63
    const int r    = lane & 31;
    const int vec  = lane >> 5;

    float w1r[68];
#pragma unroll
    for (int c = 0; c < 67; ++c) w1r[c] = w1[r * 67 + c];
    w1r[67] = 0.0f;
    float w2r[32];
    {
        const float4* p = (const float4*)(w2 + lane * 32);
#pragma unroll
        for (int c4 = 0; c4 < 8; ++c4) {
            float4 v = p[c4];
            w2r[c4 * 4 + 0] = v.x; w2r[c4 * 4 + 1] = v.y;
            w2r[c4 * 4 + 2] = v.z; w2r[c4 * 4 + 3] = v.w;
        }
    }
    float w3r[64];
    {
        const float4* p = (const float4*)(w3 + lane * 64);
#pragma unroll
        for (int c4 = 0; c4 < 16; ++c4) {
            float4 v = p[c4];
            w3r[c4 * 4 + 0] = v.x; w3r[c4 * 4 + 1] = v.y;
            w3r[c4 * 4 + 2] = v.z; w3r[c4 * 4 + 3] = v.w;
        }
    }
    float awr[16];
#pragma unroll
    for (int k = 0; k < 16; ++k) awr[k] = aw[k];
    float sa = 0.0f;
#pragma unroll
    for (int k = 0; k < 16; ++k) sa += awr[k];
    const float b1v = b1[r], b2v = b2[lane], b3v = b3[lane], abv = ab[0];
    const float c1 = (vec == 0) ? 16.0f : sa;

    // XCD-chunk swizzle (grid = 2048 = 8 * 256)
    const int sblk = (blockIdx.x & 7) * 256 + (blockIdx.x >> 3);

#pragma unroll 1
    for (int t = 0; t < QPW; ++t) {
        const int gp = sblk * QPW + t;        // global sorted position 0..16383
        const int b  = gp >> 13;
        const int q  = sidx[(size_t)b * NPTS + (gp & (NPTS - 1))];  // original id
        const int gq = b * NPTS + q;          // output/knn row
        const u16*   pfb = pfh + (size_t)b * NPTS * 64;
        const float* cb  = coords + (size_t)b * NPTS * 3;

        int myi = knn_idx[(size_t)gq * KNB + (lane & 15)] & (NPTS - 1);

        float pool = -3.0e38f, G1 = 0.0f, Ga = 0.0f;
#pragma unroll
        for (int k = 0; k < 16; ++k) {
            int nk = __shfl(myi, k, 64);
            float v = bf2f(pfb[nk * 64 + lane]);
            pool = fmaxf(pool, v);
            G1 += v;
            Ga = fmaf(awr[k], v, Ga);
        }
        vbuf[0][lane] = G1;
        vbuf[1][lane] = Ga;

        if (lane < 48) {
            int j  = lane >> 4;
            int i0 = __shfl(myi, 0, 64);
            float rel  = cb[myi * 3 + j] - cb[i0 * 3 + j];
            float wrel = awr[lane & 15] * rel;
#pragma unroll
            for (int d = 1; d < 16; d <<= 1) {
                rel  += __shfl_xor(rel, d, 64);
                wrel += __shfl_xor(wrel, d, 64);
            }
            if ((lane & 15) == 0) { vbuf[0][64 + j] = rel; vbuf[1][64 + j] = wrel; }
        }
        if (lane == 0) { vbuf[0][67] = 0.0f; vbuf[1][67] = 0.0f; }
        __syncthreads();

        float acc = c1 * b1v;
        {
            const float4* vp = (const float4*)(&vbuf[vec][0]);
#pragma unroll
            for (int c4 = 0; c4 < 17; ++c4) {
                float4 g4 = vp[c4];
                acc = fmaf(g4.x, w1r[c4 * 4 + 0], acc);
                acc = fmaf(g4.y, w1r[c4 * 4 + 1], acc);
                acc = fmaf(g4.z, w1r[c4 * 4 + 2], acc);
                acc = fmaf(g4.w, w1r[c4 * 4 + 3], acc);
            }
        }
        h1buf[vec][r] = acc;
        __syncthreads();

        float a0 = 16.0f * b2v, a1 = sa * b2v;
        {
            const float4* p0 = (const float4*)(&h1buf[0][0]);
            const float4* p1 = (const float4*)(&h1buf[1][0]);
#pragma unroll
            for (int c4 = 0; c4 < 8; ++c4) {
                float4 x0 = p0[c4], x1 = p1[c4];
                a0 = fmaf(x0.x, w2r[c4 * 4 + 0], a0);
                a0 = fmaf(x0.y, w2r[c4 * 4 + 1], a0);
                a0 = fmaf(x0.z, w2r[c4 * 4 + 2], a0);
                a0 = fmaf(x0.w, w2r[c4 * 4 + 3], a0);
                a1 = fmaf(x1.x, w2r[c4 * 4 + 0], a1);
                a1 = fmaf(x1.y, w2r[c4 * 4 + 1], a1);
                a1 = fmaf(x1.z, w2r[c4 * 4 + 2], a1);
                a1 = fmaf(x1.w, w2r[c4 * 4 + 3], a1);
            }
        }
        __syncthreads();
        vbuf[0][lane] = a0;
        vbuf[1][lane] = a1;
        __syncthreads();

        float s1 = 16.0f * b3v, sA = sa * b3v;
        {
            const float4* p0 = (const float4*)(&vbuf[0][0]);
            const float4* p1 = (const float4*)(&vbuf[1][0]);
#pragma unroll
            for (int c4 = 0; c4 < 16; ++c4) {
                float4 x0 = p0[c4], x1 = p1[c4];
                s1 = fmaf(x0.x, w3r[c4 * 4 + 0], s1);
                s1 = fmaf(x0.y, w3r[c4 * 4 + 1], s1);
                s1 = fmaf(x0.z, w3r[c4 * 4 + 2], s1);
                s1 = fmaf(x0.w, w3r[c4 * 4 + 3], s1);
                sA = fmaf(x1.x, w3r[c4 * 4 + 0], sA);
                sA = fmaf(x1.y, w3r[c4 * 4 + 1], sA);
                sA = fmaf(x1.z, w3r[c4 * 4 + 2], sA);
                sA = fmaf(x1.w, w3r[c4 * 4 + 3], sA);
            }
        }
        float* op = out + (size_t)gq * 192;
        op[lane]       = s1;
        op[64 + lane]  = pool;
        op[128 + lane] = sA + abv;
        __syncthreads();
    }
}

extern "C" void kernel_launch(void* const* d_in, const int* in_sizes, int n_in,
                              void* d_out, int out_size, void* d_ws, size_t ws_size,
                              hipStream_t stream) {
    const float* pf     = (const float*)d_in[0];
    const float* coords = (const float*)d_in[1];
    const float* w1     = (const float*)d_in[2];
    const float* b1     = (const float*)d_in[3];
    const float* w2     = (const float*)d_in[4];
    const float* b2     = (const float*)d_in[5];
    const float* w3     = (const float*)d_in[6];
    const float* b3     = (const float*)d_in[7];
    const float* aw     = (const float*)d_in[8];
    const float* ab     = (const float*)d_in[9];

    char* ws = (char*)d_ws;
    int*    knn_idx    = (int*)ws;                              // 1 MB
    u16*    pfh        = (u16*)(ws + (1 << 20));                // 2 MB
    float4* spts       = (float4*)(ws + (3 << 20));             // 256 KB
    int*    sidx       = (int*)(ws + (3 << 20) + (256 << 10));  // 64 KB
    int*    cellStart  = (int*)(ws + (3 << 20) + (320 << 10));  // 2*513*4 B
    int*    counts     = (int*)(ws + (3 << 20) + (328 << 10));  // 2*512*4 B
    int*    cellOffset = (int*)(ws + (3 << 20) + (336 << 10));  // 2*512*4 B
    float*  outp       = (float*)d_out;

    hipMemsetAsync(counts, 0, 2 * 512 * sizeof(int), stream);
    pack_count_kernel<<<4096, 256, 0, stream>>>(pf, coords, pfh, counts);
    scan_kernel<<<2, 512, 0, stream>>>(counts, cellStart, cellOffset);
    scatter_kernel<<<64, 256, 0, stream>>>(coords, cellOffset, spts, sidx);
    knn_kernel<<<4096, 64, 0, stream>>>(coords, spts, sidx, cellStart, knn_idx);
    mlp_kernel<<<2048, 64, 0, stream>>>(pfh, coords, w1, b1, w2, b2, w3, b3,
                                        aw, ab, knn_idx, sidx, outp);
}